// Round 5
// baseline (231.743 us; speedup 1.0000x reference)
//
#include <hip/hip_runtime.h>
#include <hip/hip_bf16.h>

// ---------- types ----------
typedef short bf16x8 __attribute__((ext_vector_type(8)));
typedef float f32x4 __attribute__((ext_vector_type(4)));

typedef __attribute__((address_space(3))) unsigned int lds_u32;
typedef __attribute__((address_space(1))) const unsigned int gbl_cu32;

__device__ __forceinline__ void async_ld16(void* lds, const void* g) {
  __builtin_amdgcn_global_load_lds((gbl_cu32*)g, (lds_u32*)lds, 16, 0, 0);
}

__device__ __forceinline__ unsigned short f2bf(float f) {
  unsigned u = __builtin_bit_cast(unsigned, f);
  u += 0x7FFFu + ((u >> 16) & 1u);   // RNE; inputs finite
  return (unsigned short)(u >> 16);
}

// ---------- prep (merged): x->bf16, mask(qkv_w), mask(proj_w) ----------
__global__ void k_prep(const float* __restrict__ x, unsigned short* __restrict__ xo,
                       const float* __restrict__ w1, const float* __restrict__ m1,
                       unsigned short* __restrict__ o1,
                       const float* __restrict__ w2, const float* __restrict__ m2,
                       unsigned short* __restrict__ o2) {
  int blk = blockIdx.x;
  if (blk < 6144) {
    int i = blk * 256 + threadIdx.x;
    float4 v = ((const float4*)x)[i];
    ushort4 r;
    r.x = f2bf(v.x); r.y = f2bf(v.y); r.z = f2bf(v.z); r.w = f2bf(v.w);
    ((ushort4*)xo)[i] = r;
  } else if (blk < 6144 + 1728) {
    int i = (blk - 6144) * 256 + threadIdx.x;
    float4 wv = ((const float4*)w1)[i];
    float4 mv = ((const float4*)m1)[i];
    ushort4 r;
    r.x = f2bf(mv.x >= 0.005f ? wv.x : 0.0f);
    r.y = f2bf(mv.y >= 0.005f ? wv.y : 0.0f);
    r.z = f2bf(mv.z >= 0.005f ? wv.z : 0.0f);
    r.w = f2bf(mv.w >= 0.005f ? wv.w : 0.0f);
    ((ushort4*)o1)[i] = r;
  } else {
    int i = (blk - 6144 - 1728) * 256 + threadIdx.x;
    float4 wv = ((const float4*)w2)[i];
    float4 mv = ((const float4*)m2)[i];
    ushort4 r;
    r.x = f2bf(mv.x >= 0.005f ? wv.x : 0.0f);
    r.y = f2bf(mv.y >= 0.005f ? wv.y : 0.0f);
    r.z = f2bf(mv.z >= 0.005f ? wv.z : 0.0f);
    r.w = f2bf(mv.w >= 0.005f ? wv.w : 0.0f);
    ((ushort4*)o2)[i] = r;
  }
}

// ---------- GEMM: C[M,N] = A[M,K] * B[N,K]^T + bias[N] ----------
// 128x128 tile, BK=64, XOR-swizzled LDS (conflict-free), lds-dma staging.
template <bool OUT_BF16>
__global__ __launch_bounds__(256) void k_gemm_bt(
    const unsigned short* __restrict__ A,
    const unsigned short* __restrict__ Bw,
    const float* __restrict__ bias,
    void* __restrict__ Cout,
    int M, int Nn, int K)
{
  __shared__ unsigned short As[128 * 64];
  __shared__ unsigned short Bs[128 * 64];
  const int tid = threadIdx.x, lane = tid & 63;
  const int wv = tid >> 6, wr = wv >> 1, wc = wv & 1;
  const int q4 = lane >> 4, r = lane & 15;
  const long bm = (long)blockIdx.x * 128, bn = (long)blockIdx.y * 128;

  f32x4 acc[4][4] = {};

  int srow[4], sco[4];
#pragma unroll
  for (int j = 0; j < 4; ++j) {
    const int s = j * 256 + tid;
    srow[j] = s >> 3;
    sco[j] = ((s & 7) ^ (srow[j] & 7)) * 16;
  }

  for (int k0 = 0; k0 < K; k0 += 64) {
    __syncthreads();
#pragma unroll
    for (int j = 0; j < 4; ++j) {
      const int ldsoff = j * 4096 + tid * 16;
      async_ld16((char*)As + ldsoff,
                 (const char*)(A + (bm + srow[j]) * (long)K + k0) + sco[j]);
      async_ld16((char*)Bs + ldsoff,
                 (const char*)(Bw + (bn + srow[j]) * (long)K + k0) + sco[j]);
    }
    __syncthreads();

#pragma unroll
    for (int ks = 0; ks < 2; ++ks) {
      bf16x8 af[4], bfr[4];
#pragma unroll
      for (int i = 0; i < 4; ++i) {
        const int row = wr * 64 + i * 16 + r;
        const int ch = (ks * 4 + q4) ^ (row & 7);
        af[i] = *(const bf16x8*)(As + row * 64 + ch * 8);
      }
#pragma unroll
      for (int j = 0; j < 4; ++j) {
        const int row = wc * 64 + j * 16 + r;
        const int ch = (ks * 4 + q4) ^ (row & 7);
        bfr[j] = *(const bf16x8*)(Bs + row * 64 + ch * 8);
      }
#pragma unroll
      for (int i = 0; i < 4; ++i)
#pragma unroll
        for (int j = 0; j < 4; ++j)
          acc[i][j] = __builtin_amdgcn_mfma_f32_16x16x32_bf16(af[i], bfr[j], acc[i][j], 0, 0, 0);
    }
  }

#pragma unroll
  for (int j = 0; j < 4; ++j) {
    const long col = bn + wc * 64 + j * 16 + r;
    const float bv = bias[col];
#pragma unroll
    for (int i = 0; i < 4; ++i) {
#pragma unroll
      for (int rr = 0; rr < 4; ++rr) {
        const long rowg = bm + wr * 64 + i * 16 + q4 * 4 + rr;
        const float v = acc[i][j][rr] + bv;
        if (OUT_BF16)
          ((unsigned short*)Cout)[rowg * Nn + col] = f2bf(v);
        else
          ((float*)Cout)[rowg * Nn + col] = v;
      }
    }
  }
}

// ---------- transpose V: qkv[b,n,2C + h*64 + d] -> vt[(bh*64+d)*1024 + n] ----------
__global__ __launch_bounds__(256) void k_transpose_v(const unsigned short* __restrict__ qkv,
                                                     unsigned short* __restrict__ vt) {
  __shared__ unsigned short T[64][72];
  const int tid = threadIdx.x;
  const int bh = blockIdx.y, b = bh / 12, h = bh % 12;
  const int n0 = blockIdx.x * 64;
#pragma unroll
  for (int i = 0; i < 2; ++i) {
    int c = tid + i * 256, row = c >> 3, ch = c & 7;
    uint4 v = *(const uint4*)(qkv + ((long)(b * 1024 + n0 + row)) * 2304 + 1536 + h * 64 + ch * 8);
    *(uint4*)(&T[row][ch * 8]) = v;
  }
  __syncthreads();
#pragma unroll
  for (int i = 0; i < 2; ++i) {
    int c = tid + i * 256, d = c >> 3, ch = c & 7;
    unsigned short tmp[8];
#pragma unroll
    for (int j = 0; j < 8; ++j) tmp[j] = T[ch * 8 + j][d];
    *(uint4*)(vt + ((long)bh * 64 + d) * 1024 + n0 + ch * 8) = *(const uint4*)tmp;
  }
}

// ---------- flash attention (v3b: dbuf K/V + reg prefetch, 1 barrier/iter, LD=68) ----------
// grid (96 bh, 8 qtile): same-bh blocks land on one XCD (96 % 8 == 0) -> K/V L2 reuse.
// Ps is per-wave: P store->read needs no barrier (lgkmcnt only).
// v3 bug fixed: V prefetch slides along n (column), NOT along d (row).
__global__ __launch_bounds__(256) void k_flash(
    const unsigned short* __restrict__ qkv,  // [8192, 2304]
    const unsigned short* __restrict__ vt,   // [96*64, 1024]
    unsigned short* __restrict__ outp)       // [8192, 768]
{
  constexpr int LD = 68;  // 136 B row stride == 8 mod 128 -> conflict-free stores/reads
  __shared__ unsigned short Ks[2][64 * LD];
  __shared__ unsigned short Vts[2][64 * LD];
  __shared__ unsigned short Ps[4 * 32 * LD];

  const int tid = threadIdx.x, lane = tid & 63;
  const int wv = tid >> 6, q4 = lane >> 4, r = lane & 15;
  const int bh = blockIdx.x, b = bh / 12, h = bh % 12;
  const int q0 = blockIdx.y * 128;
  const long qrow0 = (long)b * 1024;

  const int srow0 = tid >> 3, sch = tid & 7;  // staging: rows 0..31 (i=0) / 32..63 (i=1)
  const unsigned short* kbase = qkv + qrow0 * 2304 + 768 + h * 64 + sch * 8;
  const unsigned short* vbase = vt + ((long)bh * 64) * 1024 + sch * 8;

  // Q fragments in registers for the whole kernel (A-layout)
  bf16x8 aq[2][2];
#pragma unroll
  for (int i = 0; i < 2; ++i)
#pragma unroll
    for (int kc = 0; kc < 2; ++kc)
      aq[i][kc] = *(const bf16x8*)(qkv + (qrow0 + q0 + wv * 32 + i * 16 + r) * 2304 + h * 64 + kc * 32 + q4 * 8);

  // prime: load kt=0 and stage into buf 0
  uint4 pk[2], pv[2];
#pragma unroll
  for (int i = 0; i < 2; ++i) {
    const int row = srow0 + i * 32;
    pk[i] = *(const uint4*)(kbase + (long)row * 2304);
    pv[i] = *(const uint4*)(vbase + (long)row * 1024);
  }
#pragma unroll
  for (int i = 0; i < 2; ++i) {
    const int row = srow0 + i * 32;
    *(uint4*)(&Ks[0][row * LD + sch * 8]) = pk[i];
    *(uint4*)(&Vts[0][row * LD + sch * 8]) = pv[i];
  }

  f32x4 o[2][4] = {};
  f32x4 lsum[2] = {};
  const bf16x8 ones = {0x3F80, 0x3F80, 0x3F80, 0x3F80, 0x3F80, 0x3F80, 0x3F80, 0x3F80};

  for (int kt = 0; kt < 16; ++kt) {
    const int cur = kt & 1;
    __syncthreads();  // buf[cur] writes visible; prior reads of buf[1-cur] complete

    if (kt < 15) {  // issue next tile's loads early; consumed by the ds_writes below
      const int n1 = (kt + 1) * 64;
#pragma unroll
      for (int i = 0; i < 2; ++i) {
        const int krow = n1 + srow0 + i * 32;            // K: token index advances with kt
        pk[i] = *(const uint4*)(kbase + (long)krow * 2304);
        pv[i] = *(const uint4*)(vbase + (long)(srow0 + i * 32) * 1024 + n1);  // V^T: d fixed, n advances
      }
    }

    // S = Q K^T  (32x64 per wave)
    f32x4 s[2][4] = {};
    {
      bf16x8 bk[4][2];
#pragma unroll
      for (int j = 0; j < 4; ++j)
#pragma unroll
        for (int kc = 0; kc < 2; ++kc)
          bk[j][kc] = *(const bf16x8*)(&Ks[cur][(j * 16 + r) * LD + kc * 32 + q4 * 8]);
#pragma unroll
      for (int i = 0; i < 2; ++i)
#pragma unroll
        for (int j = 0; j < 4; ++j) {
          s[i][j] = __builtin_amdgcn_mfma_f32_16x16x32_bf16(aq[i][0], bk[j][0], s[i][j], 0, 0, 0);
          s[i][j] = __builtin_amdgcn_mfma_f32_16x16x32_bf16(aq[i][1], bk[j][1], s[i][j], 0, 0, 0);
        }
    }

    // P = exp2(S*scale*log2e - 2*log2e) -> per-wave LDS (C-layout -> A-layout)
#pragma unroll
    for (int i = 0; i < 2; ++i)
#pragma unroll
      for (int j = 0; j < 4; ++j)
#pragma unroll
        for (int rr = 0; rr < 4; ++rr) {
          float p = exp2f(fmaf(s[i][j][rr], 0.1803368801f, -2.885390082f));
          Ps[(wv * 32 + i * 16 + q4 * 4 + rr) * LD + j * 16 + r] = f2bf(p);
        }

    // O += P V ; l += P . ones
    {
      bf16x8 bv[4][2];
#pragma unroll
      for (int jd = 0; jd < 4; ++jd)
#pragma unroll
        for (int kc = 0; kc < 2; ++kc)
          bv[jd][kc] = *(const bf16x8*)(&Vts[cur][(jd * 16 + r) * LD + kc * 32 + q4 * 8]);
#pragma unroll
      for (int i = 0; i < 2; ++i) {
        bf16x8 ap0 = *(const bf16x8*)(Ps + (wv * 32 + i * 16 + r) * LD + 0 + q4 * 8);
        bf16x8 ap1 = *(const bf16x8*)(Ps + (wv * 32 + i * 16 + r) * LD + 32 + q4 * 8);
        lsum[i] = __builtin_amdgcn_mfma_f32_16x16x32_bf16(ap0, ones, lsum[i], 0, 0, 0);
        lsum[i] = __builtin_amdgcn_mfma_f32_16x16x32_bf16(ap1, ones, lsum[i], 0, 0, 0);
#pragma unroll
        for (int jd = 0; jd < 4; ++jd) {
          o[i][jd] = __builtin_amdgcn_mfma_f32_16x16x32_bf16(ap0, bv[jd][0], o[i][jd], 0, 0, 0);
          o[i][jd] = __builtin_amdgcn_mfma_f32_16x16x32_bf16(ap1, bv[jd][1], o[i][jd], 0, 0, 0);
        }
      }
    }

    if (kt < 15) {  // stage next tile into the other buffer
#pragma unroll
      for (int i = 0; i < 2; ++i) {
        const int row = srow0 + i * 32;
        *(uint4*)(&Ks[1 - cur][row * LD + sch * 8]) = pk[i];
        *(uint4*)(&Vts[1 - cur][row * LD + sch * 8]) = pv[i];
      }
    }
  }

  // epilogue: normalize + store bf16 [B*N, 768]
#pragma unroll
  for (int i = 0; i < 2; ++i)
#pragma unroll
    for (int rr = 0; rr < 4; ++rr) {
      const float inv = 1.0f / lsum[i][rr];
      const long rowg = qrow0 + q0 + wv * 32 + i * 16 + q4 * 4 + rr;
#pragma unroll
      for (int jd = 0; jd < 4; ++jd)
        outp[rowg * 768 + h * 64 + jd * 16 + r] = f2bf(o[i][jd][rr] * inv);
    }
}

// ---------- launcher ----------
extern "C" void kernel_launch(void* const* d_in, const int* in_sizes, int n_in,
                              void* d_out, int out_size, void* d_ws, size_t ws_size,
                              hipStream_t stream) {
  const float* x      = (const float*)d_in[0];
  const float* qkv_w  = (const float*)d_in[1];
  const float* qkv_b  = (const float*)d_in[2];
  const float* proj_w = (const float*)d_in[3];
  const float* proj_b = (const float*)d_in[4];
  const float* mask   = (const float*)d_in[5];
  const float* mask_p = (const float*)d_in[6];

  char* ws = (char*)d_ws;
  unsigned short* qkv   = (unsigned short*)(ws);              // 8192*2304*2
  unsigned short* vt    = (unsigned short*)(ws + 37748736);   // 96*64*1024*2
  unsigned short* xbf   = (unsigned short*)(ws + 50331648);   // 8192*768*2 (reused as attn out)
  unsigned short* wqkv  = (unsigned short*)(ws + 62914560);   // 2304*768*2
  unsigned short* wproj = (unsigned short*)(ws + 66453504);   // 768*768*2

  k_prep<<<8448, 256, 0, stream>>>(x, xbf, qkv_w, mask, wqkv, proj_w, mask_p, wproj);
  k_gemm_bt<true><<<dim3(64, 18), 256, 0, stream>>>(xbf, wqkv, qkv_b, qkv, 8192, 2304, 768);
  k_transpose_v<<<dim3(16, 96), 256, 0, stream>>>(qkv, vt);
  k_flash<<<dim3(96, 8), 256, 0, stream>>>(qkv, vt, xbf);
  k_gemm_bt<false><<<dim3(64, 6), 256, 0, stream>>>(xbf, wproj, proj_b, d_out, 8192, 768, 768);
}